// Round 4
// baseline (485.366 us; speedup 1.0000x reference)
//
#include <hip/hip_runtime.h>
#include <stdint.h>

#define NB 4
#define NPTS 4096
#define MPTS 16384
#define CIN 256
#define CH0 512
#define CH1 512
#define CH2 256
#define ROWS (NB * MPTS)          // 65536
#define POS_OUT_OFF (ROWS * CH2)               // 16777216
#define BATCH_OUT_OFF (POS_OUT_OFF + ROWS * 3) // 16973824

using u16 = unsigned short;
using u32 = unsigned int;

typedef __bf16 bf16x8 __attribute__((ext_vector_type(8)));
typedef float f32x4 __attribute__((ext_vector_type(4)));

__device__ __forceinline__ u16 f2bf(float f) {
  u32 u = __builtin_bit_cast(u32, f);
  u32 r = u + 0x7fffu + ((u >> 16) & 1u);   // round-to-nearest-even
  return (u16)(r >> 16);
}

// ---------------------------------------------------------------- W prep
__global__ __launch_bounds__(256) void prep_kernel(
    const float* __restrict__ W1, const float* __restrict__ W2,
    u16* __restrict__ W1T, u16* __restrict__ W2T) {
  int t = blockIdx.x * 256 + threadIdx.x;
  if (t < CH0 * CH1) {
    int n = t >> 9, k = t & 511;
    W1T[t] = f2bf(W1[k * CH1 + n]);
  } else {
    int u = t - CH0 * CH1;
    int n = u >> 9, k = u & 511;
    W2T[u] = f2bf(W2[k * CH2 + n]);
  }
}

// ---------------------------------------------------------------- tail copy
__global__ __launch_bounds__(256) void tail_kernel(
    const float* __restrict__ pos_skip, const int* __restrict__ batch_skip,
    float* __restrict__ out) {
  int t = blockIdx.x * 256 + threadIdx.x;   // 262144 total
  if (t < ROWS * 3) {
    out[POS_OUT_OFF + t] = pos_skip[t];
  } else {
    int u = t - ROWS * 3;
    out[BATCH_OUT_OFF + u] = (float)batch_skip[u];
  }
}

// ---------------------------------------------------------------- KNN (k=3)
// Ranking metric replicates the np/XLA-CPU expanded-form f32 arithmetic:
//   p2  = (px*px + py*py) + pz*pz            (elementwise+reduce, no FMA)
//   q2  = (qx*qx + qy*qy) + qz*qz
//   dot = fma(qz,pz, fma(qy,py, RN(qx*px)))  (batched-sgemm ascending-k FMA)
//   d2  = (q2 - 2.0f*dot) + p2               (python expr order, no FMA)
// Ties -> lower index. Weights from the SELECTED noisy f32 d2.
__global__ __launch_bounds__(256) void knn_kernel(
    const float* __restrict__ pos, const float* __restrict__ pos_skip,
    int* __restrict__ idx_out, float* __restrict__ w_out) {
#pragma clang fp contract(off)
  __shared__ __align__(16) float sx[NPTS];
  __shared__ __align__(16) float sy[NPTS];
  __shared__ __align__(16) float sz[NPTS];
  __shared__ __align__(16) float sp2[NPTS];
  const int q = blockIdx.x * 256 + threadIdx.x;   // 256 blocks
  const int b = q >> 14;                          // / MPTS
  const float* pb = pos + (size_t)b * NPTS * 3;
  for (int i = threadIdx.x; i < NPTS; i += 256) {
    float x = pb[i * 3 + 0], y = pb[i * 3 + 1], z = pb[i * 3 + 2];
    sx[i] = x; sy[i] = y; sz[i] = z;
    sp2[i] = (x * x + y * y) + z * z;             // contract(off): no fma
  }
  __syncthreads();
  const float qx = pos_skip[q * 3 + 0], qy = pos_skip[q * 3 + 1], qz = pos_skip[q * 3 + 2];
  const float q2 = (qx * qx + qy * qy) + qz * qz;

  float d0 = 3.4e38f, d1 = 3.4e38f, d2s = 3.4e38f;
  int i0 = 0, i1 = 0, i2 = 0;

  for (int i = 0; i < NPTS; i += 4) {
    const float4 X = *(const float4*)&sx[i];
    const float4 Y = *(const float4*)&sy[i];
    const float4 Z = *(const float4*)&sz[i];
    const float4 P = *(const float4*)&sp2[i];
#pragma unroll
    for (int j = 0; j < 4; ++j) {
      const float px = j == 0 ? X.x : j == 1 ? X.y : j == 2 ? X.z : X.w;
      const float py = j == 0 ? Y.x : j == 1 ? Y.y : j == 2 ? Y.z : Y.w;
      const float pz = j == 0 ? Z.x : j == 1 ? Z.y : j == 2 ? Z.z : Z.w;
      const float p2 = j == 0 ? P.x : j == 1 ? P.y : j == 2 ? P.z : P.w;
      // ascending-k FMA chain (BLAS/Eigen sgemm K=3 micro-kernel order)
      const float dot = fmaf(qz, pz, fmaf(qy, py, qx * px));
      const float t = (q2 - 2.0f * dot) + p2;            // np rounding order
      if (t < d2s) {                 // strict <: tie keeps lower index
        if (t < d1) {
          d2s = d1; i2 = i1;
          if (t < d0) { d1 = d0; i1 = i0; d0 = t; i0 = i + j; }
          else        { d1 = t;  i1 = i + j; }
        } else { d2s = t; i2 = i + j; }
      }
    }
  }

  const float w0 = 1.0f / fmaxf(d0, 1e-16f);
  const float w1 = 1.0f / fmaxf(d1, 1e-16f);
  const float w2 = 1.0f / fmaxf(d2s, 1e-16f);
  const float wsum = (w0 + w1) + w2;
  const float inv = 1.0f / wsum;
  const int base = b * NPTS;
  idx_out[q * 3 + 0] = base + i0;
  idx_out[q * 3 + 1] = base + i1;
  idx_out[q * 3 + 2] = base + i2;
  w_out[q * 3 + 0] = w0 * inv;
  w_out[q * 3 + 1] = w1 * inv;
  w_out[q * 3 + 2] = w2 * inv;
}

// ---------------------------------------------------------------- interp + concat -> bf16
__global__ __launch_bounds__(256) void interp_kernel(
    const float* __restrict__ x, const int* __restrict__ idx,
    const float* __restrict__ w, const float* __restrict__ x_skip,
    u16* __restrict__ H) {
  const int row = blockIdx.x * 4 + (threadIdx.x >> 6);
  const int lane = threadIdx.x & 63;
  const int i0 = idx[row * 3 + 0], i1 = idx[row * 3 + 1], i2 = idx[row * 3 + 2];
  const float w0 = w[row * 3 + 0], w1 = w[row * 3 + 1], w2 = w[row * 3 + 2];
  const float4 a0 = ((const float4*)(x + (size_t)i0 * CIN))[lane];
  const float4 a1 = ((const float4*)(x + (size_t)i1 * CIN))[lane];
  const float4 a2 = ((const float4*)(x + (size_t)i2 * CIN))[lane];
  const float4 s  = ((const float4*)(x_skip + (size_t)row * CIN))[lane];
  float y0 = fmaf(w0, a0.x, fmaf(w1, a1.x, w2 * a2.x));
  float y1 = fmaf(w0, a0.y, fmaf(w1, a1.y, w2 * a2.y));
  float y2 = fmaf(w0, a0.z, fmaf(w1, a1.z, w2 * a2.z));
  float y3 = fmaf(w0, a0.w, fmaf(w1, a1.w, w2 * a2.w));
  u16* rp = H + (size_t)row * CH0;
  u32 lo = (u32)f2bf(y0) | ((u32)f2bf(y1) << 16);
  u32 hi = (u32)f2bf(y2) | ((u32)f2bf(y3) << 16);
  *(uint2*)(rp + lane * 4) = make_uint2(lo, hi);
  lo = (u32)f2bf(s.x) | ((u32)f2bf(s.y) << 16);
  hi = (u32)f2bf(s.z) | ((u32)f2bf(s.w) << 16);
  *(uint2*)(rp + CIN + lane * 4) = make_uint2(lo, hi);
}

// ---------------------------------------------------------------- GEMM (m97-style)
__device__ __forceinline__ void gload_lds16(const u16* g, u16* l) {
  __builtin_amdgcn_global_load_lds(
      (__attribute__((address_space(1))) void*)g,
      (__attribute__((address_space(3))) void*)l, 16, 0, 0);
}

template <int KD, int ND, bool OUT_BF16>
__global__ __launch_bounds__(256) void gemm_kernel(
    const u16* __restrict__ A, const u16* __restrict__ Bt,
    const float* __restrict__ bias, void* __restrict__ Cout) {
  __shared__ __align__(16) u16 As[128 * 32];
  __shared__ __align__(16) u16 Bs[128 * 32];
  const int wid = threadIdx.x >> 6;
  const int lane = threadIdx.x & 63;
  const size_t arow0 = (size_t)blockIdx.x * 128;
  const size_t brow0 = (size_t)blockIdx.y * 128;
  const int c0 = wid * 2, c1 = wid * 2 + 1;
  const int lr = lane >> 2;
  const int lk = (lane & 3) * 8;
  const u16* gA0 = A + (arow0 + c0 * 16 + lr) * KD + lk;
  const u16* gA1 = A + (arow0 + c1 * 16 + lr) * KD + lk;
  const u16* gB0 = Bt + (brow0 + c0 * 16 + lr) * KD + lk;
  const u16* gB1 = Bt + (brow0 + c1 * 16 + lr) * KD + lk;
  u16* lA0 = As + c0 * 512 + lane * 8;
  u16* lA1 = As + c1 * 512 + lane * 8;
  u16* lB0 = Bs + c0 * 512 + lane * 8;
  u16* lB1 = Bs + c1 * 512 + lane * 8;

  f32x4 acc[4][4];
#pragma unroll
  for (int mi = 0; mi < 4; mi++)
#pragma unroll
    for (int ni = 0; ni < 4; ni++) acc[mi][ni] = (f32x4){0.f, 0.f, 0.f, 0.f};

  const int wr = (wid >> 1) * 64;
  const int wc = (wid & 1) * 64;
  const int fr = lane & 15;
  const int fk = (lane >> 4) * 8;

  for (int k0 = 0; k0 < KD; k0 += 32) {
    gload_lds16(gA0 + k0, lA0);
    gload_lds16(gA1 + k0, lA1);
    gload_lds16(gB0 + k0, lB0);
    gload_lds16(gB1 + k0, lB1);
    __syncthreads();
    bf16x8 af[4], bfr[4];
#pragma unroll
    for (int mi = 0; mi < 4; mi++)
      af[mi] = *(const bf16x8*)&As[(wr + mi * 16 + fr) * 32 + fk];
#pragma unroll
    for (int ni = 0; ni < 4; ni++)
      bfr[ni] = *(const bf16x8*)&Bs[(wc + ni * 16 + fr) * 32 + fk];
#pragma unroll
    for (int mi = 0; mi < 4; mi++)
#pragma unroll
      for (int ni = 0; ni < 4; ni++)
        acc[mi][ni] = __builtin_amdgcn_mfma_f32_16x16x32_bf16(
            af[mi], bfr[ni], acc[mi][ni], 0, 0, 0);
    __syncthreads();
  }

  const int rbase = (int)arow0 + wr + (lane >> 4) * 4;
  const int cbase = (int)brow0 + wc + fr;
#pragma unroll
  for (int ni = 0; ni < 4; ni++) {
    const int colg = cbase + ni * 16;
    const float bc = bias[colg];
#pragma unroll
    for (int mi = 0; mi < 4; mi++) {
#pragma unroll
      for (int r = 0; r < 4; r++) {
        float v = fmaxf(acc[mi][ni][r] + bc, 0.f);
        const size_t o = (size_t)(rbase + mi * 16 + r) * ND + colg;
        if constexpr (OUT_BF16) ((u16*)Cout)[o] = f2bf(v);
        else                    ((float*)Cout)[o] = v;
      }
    }
  }
}

// ---------------------------------------------------------------- launch
extern "C" void kernel_launch(void* const* d_in, const int* in_sizes, int n_in,
                              void* d_out, int out_size, void* d_ws, size_t ws_size,
                              hipStream_t stream) {
  const float* x        = (const float*)d_in[0];
  const float* pos      = (const float*)d_in[1];
  const float* x_skip   = (const float*)d_in[3];
  const float* pos_skip = (const float*)d_in[4];
  const int*   batch_sk = (const int*)d_in[5];
  const float* W1       = (const float*)d_in[6];
  const float* b1       = (const float*)d_in[7];
  const float* W2       = (const float*)d_in[8];
  const float* b2       = (const float*)d_in[9];
  float* out = (float*)d_out;

  char* ws = (char*)d_ws;
  u16*   W1T  = (u16*)(ws);                    // 524288 B
  u16*   W2T  = (u16*)(ws + 524288);           // 262144 B
  int*   idxb = (int*)(ws + 786432);           // 786432 B
  float* wb   = (float*)(ws + 1572864);        // 786432 B
  u16*   Hcat = (u16*)(ws + 2359296);          // 67108864 B  [65536,512] bf16
  u16*   H1   = (u16*)(ws + 69468160);         // 67108864 B  [65536,512] bf16

  prep_kernel<<<dim3(1536), dim3(256), 0, stream>>>(W1, W2, W1T, W2T);
  tail_kernel<<<dim3(1024), dim3(256), 0, stream>>>(pos_skip, batch_sk, out);
  knn_kernel<<<dim3(256), dim3(256), 0, stream>>>(pos, pos_skip, idxb, wb);
  interp_kernel<<<dim3(16384), dim3(256), 0, stream>>>(x, idxb, wb, x_skip, Hcat);
  gemm_kernel<CH0, CH1, true><<<dim3(ROWS / 128, CH1 / 128), dim3(256), 0, stream>>>(
      Hcat, W1T, b1, (void*)H1);
  gemm_kernel<CH1, CH2, false><<<dim3(ROWS / 128, CH2 / 128), dim3(256), 0, stream>>>(
      H1, W2T, b2, (void*)out);
}

// Round 5
// 395.954 us; speedup vs baseline: 1.2258x; 1.2258x over previous
//
#include <hip/hip_runtime.h>
#include <stdint.h>

#define NB 4
#define NPTS 4096
#define MPTS 16384
#define CIN 256
#define CH0 512
#define CH1 512
#define CH2 256
#define ROWS (NB * MPTS)          // 65536
#define POS_OUT_OFF (ROWS * CH2)               // 16777216
#define BATCH_OUT_OFF (POS_OUT_OFF + ROWS * 3) // 16973824

using u16 = unsigned short;
using u32 = unsigned int;

typedef __bf16 bf16x8 __attribute__((ext_vector_type(8)));
typedef float f32x4 __attribute__((ext_vector_type(4)));

__device__ __forceinline__ u16 f2bf(float f) {
  u32 u = __builtin_bit_cast(u32, f);
  u32 r = u + 0x7fffu + ((u >> 16) & 1u);   // round-to-nearest-even
  return (u16)(r >> 16);
}

// ---------------------------------------------------------------- W prep
__global__ __launch_bounds__(256) void prep_kernel(
    const float* __restrict__ W1, const float* __restrict__ W2,
    u16* __restrict__ W1T, u16* __restrict__ W2T) {
  int t = blockIdx.x * 256 + threadIdx.x;
  if (t < CH0 * CH1) {
    int n = t >> 9, k = t & 511;
    W1T[t] = f2bf(W1[k * CH1 + n]);
  } else {
    int u = t - CH0 * CH1;
    int n = u >> 9, k = u & 511;
    W2T[u] = f2bf(W2[k * CH2 + n]);
  }
}

// ---------------------------------------------------------------- pts prep
// Pack coarse points as (x, y, z, p2) with np-exact p2 rounding.
__global__ __launch_bounds__(256) void pts_prep_kernel(
    const float* __restrict__ pos, float4* __restrict__ pts4) {
#pragma clang fp contract(off)
  int i = blockIdx.x * 256 + threadIdx.x;   // 64 blocks x 256 = 16384
  float x = pos[i * 3 + 0], y = pos[i * 3 + 1], z = pos[i * 3 + 2];
  pts4[i] = make_float4(x, y, z, (x * x + y * y) + z * z);
}

// ---------------------------------------------------------------- tail copy
__global__ __launch_bounds__(256) void tail_kernel(
    const float* __restrict__ pos_skip, const int* __restrict__ batch_skip,
    float* __restrict__ out) {
  int t = blockIdx.x * 256 + threadIdx.x;   // 262144 total
  if (t < ROWS * 3) {
    out[POS_OUT_OFF + t] = pos_skip[t];
  } else {
    int u = t - ROWS * 3;
    out[BATCH_OUT_OFF + u] = (float)batch_skip[u];
  }
}

// ---------------------------------------------------------------- KNN (k=3)
// Occupancy-restructured: block = 32 queries x 8 chunks of 512 points
// (grid 2048 -> 8 blocks/CU, 32 waves/CU vs round-4's 1 block/CU).
// Phase-1: rank-equivalent shifted metric m = p2 - 2*dot (3 FMA + cmp),
//   per-(query,chunk) top-4; noise ~5e-7 << typical d3..d5 gaps ~5e-4.
// Merge: top-4 of 32 candidates by m (strict <, sequence preserves
//   index-ascending among equal m).
// Phase-2: np-exact arithmetic on the 4 survivors, bit-identical to R4:
//   dot = fma(qz,pz, fma(qy,py, qx*px)); t = (q2 - 2.0f*dot) + p2;
//   strict-< scan in ascending index order; f32 weights from selected t.
__global__ __launch_bounds__(256, 8) void knn_kernel(
    const float4* __restrict__ pts4, const float* __restrict__ pos_skip,
    int* __restrict__ idx_out, float* __restrict__ w_out) {
#pragma clang fp contract(off)
  __shared__ float md[8][32][4];
  __shared__ int   mi[8][32][4];
  const int tid = threadIdx.x;
  const int lane = tid & 63;
  const int wv = tid >> 6;
  const int qi = lane & 31;                 // query within block
  const int ch = wv * 2 + (lane >> 5);      // chunk 0..7
  const int q = blockIdx.x * 32 + qi;
  const int b = blockIdx.x >> 9;            // 512 blocks per batch
  {
    const float qx = pos_skip[q * 3 + 0];
    const float qy = pos_skip[q * 3 + 1];
    const float qz = pos_skip[q * 3 + 2];
    const float m2x = -2.0f * qx, m2y = -2.0f * qy, m2z = -2.0f * qz;
    const float4* base = pts4 + b * NPTS + ch * 512;
    float d0 = 3.4e38f, d1 = 3.4e38f, d2 = 3.4e38f, d3 = 3.4e38f;
    int i0 = 0, i1 = 0, i2 = 0, i3 = 0;
    for (int i = 0; i < 512; i += 4) {
      const float4 p0 = base[i + 0];
      const float4 p1 = base[i + 1];
      const float4 p2 = base[i + 2];
      const float4 p3 = base[i + 3];
#define STEP(P, J)                                                          \
      {                                                                     \
        const float m = fmaf(m2z, P.z, fmaf(m2y, P.y, fmaf(m2x, P.x, P.w)));\
        if (m < d3) {                                                       \
          const int g = i + (J);                                            \
          if (m < d2) {                                                     \
            d3 = d2; i3 = i2;                                               \
            if (m < d1) {                                                   \
              d2 = d1; i2 = i1;                                             \
              if (m < d0) { d1 = d0; i1 = i0; d0 = m; i0 = g; }             \
              else        { d1 = m; i1 = g; }                               \
            } else { d2 = m; i2 = g; }                                      \
          } else { d3 = m; i3 = g; }                                        \
        }                                                                   \
      }
      STEP(p0, 0) STEP(p1, 1) STEP(p2, 2) STEP(p3, 3)
#undef STEP
    }
    const int gb = b * NPTS + ch * 512;
    md[ch][qi][0] = d0; mi[ch][qi][0] = gb + i0;
    md[ch][qi][1] = d1; mi[ch][qi][1] = gb + i1;
    md[ch][qi][2] = d2; mi[ch][qi][2] = gb + i2;
    md[ch][qi][3] = d3; mi[ch][qi][3] = gb + i3;
  }
  __syncthreads();
  if (tid < 32) {
    // merge 32 candidates by phase-1 metric (strict <)
    float dd0 = 3.4e38f, dd1 = 3.4e38f, dd2 = 3.4e38f, dd3 = 3.4e38f;
    int ii0 = 0, ii1 = 0, ii2 = 0, ii3 = 0;
    for (int c = 0; c < 8; ++c) {
#pragma unroll
      for (int s = 0; s < 4; ++s) {
        const float m = md[c][tid][s];
        const int g = mi[c][tid][s];
        if (m < dd3) {
          if (m < dd2) {
            dd3 = dd2; ii3 = ii2;
            if (m < dd1) {
              dd2 = dd1; ii2 = ii1;
              if (m < dd0) { dd1 = dd0; ii1 = ii0; dd0 = m; ii0 = g; }
              else         { dd1 = m; ii1 = g; }
            } else { dd2 = m; ii2 = g; }
          } else { dd3 = m; ii3 = g; }
        }
      }
    }
    // sort the 4 survivors by global index ascending (network 5 cmp)
    int g0 = ii0, g1 = ii1, g2 = ii2, g3 = ii3;
    int t;
    if (g0 > g1) { t = g0; g0 = g1; g1 = t; }
    if (g2 > g3) { t = g2; g2 = g3; g3 = t; }
    if (g0 > g2) { t = g0; g0 = g2; g2 = t; }
    if (g1 > g3) { t = g1; g1 = g3; g3 = t; }
    if (g1 > g2) { t = g1; g1 = g2; g2 = t; }
    // phase-2: np-exact metric (R4 arithmetic), ascending-index strict-< scan
    const int qq = blockIdx.x * 32 + tid;
    const float qx = pos_skip[qq * 3 + 0];
    const float qy = pos_skip[qq * 3 + 1];
    const float qz = pos_skip[qq * 3 + 2];
    const float q2 = (qx * qx + qy * qy) + qz * qz;
    float e0 = 3.4e38f, e1 = 3.4e38f, e2 = 3.4e38f;
    int j0 = 0, j1 = 0, j2 = 0;
#define EXACT(G)                                                            \
    {                                                                       \
      const float4 p = pts4[G];                                             \
      const float dot = fmaf(qz, p.z, fmaf(qy, p.y, qx * p.x));             \
      const float tv = (q2 - 2.0f * dot) + p.w;                             \
      if (tv < e2) {                                                        \
        if (tv < e1) {                                                      \
          e2 = e1; j2 = j1;                                                 \
          if (tv < e0) { e1 = e0; j1 = j0; e0 = tv; j0 = (G); }             \
          else         { e1 = tv; j1 = (G); }                               \
        } else { e2 = tv; j2 = (G); }                                       \
      }                                                                     \
    }
    EXACT(g0) EXACT(g1) EXACT(g2) EXACT(g3)
#undef EXACT
    const float w0 = 1.0f / fmaxf(e0, 1e-16f);
    const float w1 = 1.0f / fmaxf(e1, 1e-16f);
    const float w2 = 1.0f / fmaxf(e2, 1e-16f);
    const float wsum = (w0 + w1) + w2;
    const float inv = 1.0f / wsum;
    idx_out[qq * 3 + 0] = j0;
    idx_out[qq * 3 + 1] = j1;
    idx_out[qq * 3 + 2] = j2;
    w_out[qq * 3 + 0] = w0 * inv;
    w_out[qq * 3 + 1] = w1 * inv;
    w_out[qq * 3 + 2] = w2 * inv;
  }
}

// ---------------------------------------------------------------- interp + concat -> bf16
__global__ __launch_bounds__(256) void interp_kernel(
    const float* __restrict__ x, const int* __restrict__ idx,
    const float* __restrict__ w, const float* __restrict__ x_skip,
    u16* __restrict__ H) {
  const int row = blockIdx.x * 4 + (threadIdx.x >> 6);
  const int lane = threadIdx.x & 63;
  const int i0 = idx[row * 3 + 0], i1 = idx[row * 3 + 1], i2 = idx[row * 3 + 2];
  const float w0 = w[row * 3 + 0], w1 = w[row * 3 + 1], w2 = w[row * 3 + 2];
  const float4 a0 = ((const float4*)(x + (size_t)i0 * CIN))[lane];
  const float4 a1 = ((const float4*)(x + (size_t)i1 * CIN))[lane];
  const float4 a2 = ((const float4*)(x + (size_t)i2 * CIN))[lane];
  const float4 s  = ((const float4*)(x_skip + (size_t)row * CIN))[lane];
  float y0 = fmaf(w0, a0.x, fmaf(w1, a1.x, w2 * a2.x));
  float y1 = fmaf(w0, a0.y, fmaf(w1, a1.y, w2 * a2.y));
  float y2 = fmaf(w0, a0.z, fmaf(w1, a1.z, w2 * a2.z));
  float y3 = fmaf(w0, a0.w, fmaf(w1, a1.w, w2 * a2.w));
  u16* rp = H + (size_t)row * CH0;
  u32 lo = (u32)f2bf(y0) | ((u32)f2bf(y1) << 16);
  u32 hi = (u32)f2bf(y2) | ((u32)f2bf(y3) << 16);
  *(uint2*)(rp + lane * 4) = make_uint2(lo, hi);
  lo = (u32)f2bf(s.x) | ((u32)f2bf(s.y) << 16);
  hi = (u32)f2bf(s.z) | ((u32)f2bf(s.w) << 16);
  *(uint2*)(rp + CIN + lane * 4) = make_uint2(lo, hi);
}

// ---------------------------------------------------------------- GEMM (m97-style)
__device__ __forceinline__ void gload_lds16(const u16* g, u16* l) {
  __builtin_amdgcn_global_load_lds(
      (__attribute__((address_space(1))) void*)g,
      (__attribute__((address_space(3))) void*)l, 16, 0, 0);
}

template <int KD, int ND, bool OUT_BF16>
__global__ __launch_bounds__(256) void gemm_kernel(
    const u16* __restrict__ A, const u16* __restrict__ Bt,
    const float* __restrict__ bias, void* __restrict__ Cout) {
  __shared__ __align__(16) u16 As[128 * 32];
  __shared__ __align__(16) u16 Bs[128 * 32];
  const int wid = threadIdx.x >> 6;
  const int lane = threadIdx.x & 63;
  const size_t arow0 = (size_t)blockIdx.x * 128;
  const size_t brow0 = (size_t)blockIdx.y * 128;
  const int c0 = wid * 2, c1 = wid * 2 + 1;
  const int lr = lane >> 2;
  const int lk = (lane & 3) * 8;
  const u16* gA0 = A + (arow0 + c0 * 16 + lr) * KD + lk;
  const u16* gA1 = A + (arow0 + c1 * 16 + lr) * KD + lk;
  const u16* gB0 = Bt + (brow0 + c0 * 16 + lr) * KD + lk;
  const u16* gB1 = Bt + (brow0 + c1 * 16 + lr) * KD + lk;
  u16* lA0 = As + c0 * 512 + lane * 8;
  u16* lA1 = As + c1 * 512 + lane * 8;
  u16* lB0 = Bs + c0 * 512 + lane * 8;
  u16* lB1 = Bs + c1 * 512 + lane * 8;

  f32x4 acc[4][4];
#pragma unroll
  for (int mi = 0; mi < 4; mi++)
#pragma unroll
    for (int ni = 0; ni < 4; ni++) acc[mi][ni] = (f32x4){0.f, 0.f, 0.f, 0.f};

  const int wr = (wid >> 1) * 64;
  const int wc = (wid & 1) * 64;
  const int fr = lane & 15;
  const int fk = (lane >> 4) * 8;

  for (int k0 = 0; k0 < KD; k0 += 32) {
    gload_lds16(gA0 + k0, lA0);
    gload_lds16(gA1 + k0, lA1);
    gload_lds16(gB0 + k0, lB0);
    gload_lds16(gB1 + k0, lB1);
    __syncthreads();
    bf16x8 af[4], bfr[4];
#pragma unroll
    for (int mi = 0; mi < 4; mi++)
      af[mi] = *(const bf16x8*)&As[(wr + mi * 16 + fr) * 32 + fk];
#pragma unroll
    for (int ni = 0; ni < 4; ni++)
      bfr[ni] = *(const bf16x8*)&Bs[(wc + ni * 16 + fr) * 32 + fk];
#pragma unroll
    for (int mi = 0; mi < 4; mi++)
#pragma unroll
      for (int ni = 0; ni < 4; ni++)
        acc[mi][ni] = __builtin_amdgcn_mfma_f32_16x16x32_bf16(
            af[mi], bfr[ni], acc[mi][ni], 0, 0, 0);
    __syncthreads();
  }

  const int rbase = (int)arow0 + wr + (lane >> 4) * 4;
  const int cbase = (int)brow0 + wc + fr;
#pragma unroll
  for (int ni = 0; ni < 4; ni++) {
    const int colg = cbase + ni * 16;
    const float bc = bias[colg];
#pragma unroll
    for (int mi = 0; mi < 4; mi++) {
#pragma unroll
      for (int r = 0; r < 4; r++) {
        float v = fmaxf(acc[mi][ni][r] + bc, 0.f);
        const size_t o = (size_t)(rbase + mi * 16 + r) * ND + colg;
        if constexpr (OUT_BF16) ((u16*)Cout)[o] = f2bf(v);
        else                    ((float*)Cout)[o] = v;
      }
    }
  }
}

// ---------------------------------------------------------------- launch
extern "C" void kernel_launch(void* const* d_in, const int* in_sizes, int n_in,
                              void* d_out, int out_size, void* d_ws, size_t ws_size,
                              hipStream_t stream) {
  const float* x        = (const float*)d_in[0];
  const float* pos      = (const float*)d_in[1];
  const float* x_skip   = (const float*)d_in[3];
  const float* pos_skip = (const float*)d_in[4];
  const int*   batch_sk = (const int*)d_in[5];
  const float* W1       = (const float*)d_in[6];
  const float* b1       = (const float*)d_in[7];
  const float* W2       = (const float*)d_in[8];
  const float* b2       = (const float*)d_in[9];
  float* out = (float*)d_out;

  char* ws = (char*)d_ws;
  u16*   W1T  = (u16*)(ws);                    // 524288 B
  u16*   W2T  = (u16*)(ws + 524288);           // 262144 B
  int*   idxb = (int*)(ws + 786432);           // 786432 B
  float* wb   = (float*)(ws + 1572864);        // 786432 B
  u16*   Hcat = (u16*)(ws + 2359296);          // 67108864 B  [65536,512] bf16
  u16*   H1   = (u16*)(ws + 69468160);         // 67108864 B  [65536,512] bf16
  // pts4 aliases the start of H1: knn (reader) completes before gemm1
  // (writer of H1) launches on the same stream.
  float4* pts4 = (float4*)(ws + 69468160);     // 262144 B

  prep_kernel<<<dim3(1536), dim3(256), 0, stream>>>(W1, W2, W1T, W2T);
  tail_kernel<<<dim3(1024), dim3(256), 0, stream>>>(pos_skip, batch_sk, out);
  pts_prep_kernel<<<dim3(64), dim3(256), 0, stream>>>(pos, pts4);
  knn_kernel<<<dim3(2048), dim3(256), 0, stream>>>(pts4, pos_skip, idxb, wb);
  interp_kernel<<<dim3(16384), dim3(256), 0, stream>>>(x, idxb, wb, x_skip, Hcat);
  gemm_kernel<CH0, CH1, true><<<dim3(ROWS / 128, CH1 / 128), dim3(256), 0, stream>>>(
      Hcat, W1T, b1, (void*)H1);
  gemm_kernel<CH1, CH2, false><<<dim3(ROWS / 128, CH2 / 128), dim3(256), 0, stream>>>(
      H1, W2T, b2, (void*)out);
}